// Round 1
// baseline (1515.605 us; speedup 1.0000x reference)
//
#include <hip/hip_runtime.h>
#include <cmath>

constexpr int NN  = 100000;
constexpr int FIN = 128;
constexpr int HH  = 64;
constexpr int NE  = 3200000;

// deg[i] = 1 (self loop)
__global__ void k_deg_init(int* __restrict__ deg) {
    int i = blockIdx.x * blockDim.x + threadIdx.x;
    if (i < NN) deg[i] = 1;
}

// deg[col[e]] += 1
__global__ void k_count(const int* __restrict__ col, int* __restrict__ deg) {
    int stride = gridDim.x * blockDim.x;
    for (int e = blockIdx.x * blockDim.x + threadIdx.x; e < NE; e += stride)
        atomicAdd(&deg[col[e]], 1);
}

// dis[i] = rsqrt(deg[i])   (deg >= 1 always)
__global__ void k_dis(const int* __restrict__ deg, float* __restrict__ dis) {
    int i = blockIdx.x * blockDim.x + threadIdx.x;
    if (i < NN) dis[i] = rsqrtf((float)deg[i]);
}

// xt = x @ W_gcn   (N x 128) @ (128 x 64)
__global__ void __launch_bounds__(256) k_xt(const float* __restrict__ x,
                                            const float* __restrict__ W,
                                            float* __restrict__ xt) {
    __shared__ float Wl[FIN * HH];  // 32 KB
    for (int t = threadIdx.x; t < FIN * HH; t += blockDim.x) Wl[t] = W[t];
    __syncthreads();
    int lane = threadIdx.x & 63;
    int wave = threadIdx.x >> 6;
    int wpb  = blockDim.x >> 6;
    for (int row = blockIdx.x * wpb + wave; row < NN; row += gridDim.x * wpb) {
        const float* xr = x + (size_t)row * FIN;
        float acc = 0.f;
#pragma unroll 16
        for (int k = 0; k < FIN; ++k) acc = fmaf(xr[k], Wl[k * HH + lane], acc);
        xt[(size_t)row * HH + lane] = acc;
    }
}

// agg[i][c] = dis[i]^2 * xt[i][c]   (self-loop contribution; also inits agg)
__global__ void k_self(const float* __restrict__ dis, const float* __restrict__ xt,
                       float* __restrict__ agg) {
    int idx = blockIdx.x * blockDim.x + threadIdx.x;
    if (idx < NN * HH) {
        float d = dis[idx >> 6];
        agg[idx] = d * d * xt[idx];
    }
}

// wave per edge: lane c scatters one feature
__global__ void k_edge(const int* __restrict__ ei, const float* __restrict__ dis,
                       const float* __restrict__ xt, float* __restrict__ agg) {
    int lane = threadIdx.x & 63;
    int wid  = (blockIdx.x * blockDim.x + threadIdx.x) >> 6;
    int nw   = (gridDim.x * blockDim.x) >> 6;
    for (int e = wid; e < NE; e += nw) {
        int r = ei[e];        // source
        int c = ei[NE + e];   // target
        float nrm = dis[r] * dis[c];
        atomicAdd(&agg[c * HH + lane], nrm * xt[r * HH + lane]);
    }
}

// fused: g = relu(agg + b_gcn); GRU step; write out twice
__global__ void __launch_bounds__(256) k_gru(
    const float* __restrict__ agg, const float* __restrict__ bg,
    const float* __restrict__ hprev,
    const float* __restrict__ Wih, const float* __restrict__ Whh,
    const float* __restrict__ bih, const float* __restrict__ bhh,
    float* __restrict__ out) {
    int n = blockIdx.x * blockDim.x + threadIdx.x;
    if (n >= NN) return;
    float g[HH], h[HH];
    const float* ar = agg + (size_t)n * HH;
    const float* hr = hprev + (size_t)n * HH;
#pragma unroll
    for (int k = 0; k < HH; k += 4) {
        float4 a = *(const float4*)(ar + k);
        float4 b = *(const float4*)(hr + k);
        g[k]     = fmaxf(a.x + bg[k],     0.f);
        g[k + 1] = fmaxf(a.y + bg[k + 1], 0.f);
        g[k + 2] = fmaxf(a.z + bg[k + 2], 0.f);
        g[k + 3] = fmaxf(a.w + bg[k + 3], 0.f);
        h[k] = b.x; h[k + 1] = b.y; h[k + 2] = b.z; h[k + 3] = b.w;
    }
    float* o1 = out + (size_t)n * HH;
    float* o2 = out + (size_t)NN * HH + (size_t)n * HH;
#pragma unroll 1
    for (int j = 0; j < HH; ++j) {
        float ir = bih[j], iz = bih[j + HH], in_ = bih[j + 2 * HH];
        float hr_ = bhh[j], hz = bhh[j + HH], hn = bhh[j + 2 * HH];
        const float* wi0 = Wih + (size_t)j * HH;
        const float* wi1 = Wih + (size_t)(j + HH) * HH;
        const float* wi2 = Wih + (size_t)(j + 2 * HH) * HH;
        const float* wh0 = Whh + (size_t)j * HH;
        const float* wh1 = Whh + (size_t)(j + HH) * HH;
        const float* wh2 = Whh + (size_t)(j + 2 * HH) * HH;
#pragma unroll
        for (int k = 0; k < HH; ++k) {
            ir  = fmaf(wi0[k], g[k], ir);
            iz  = fmaf(wi1[k], g[k], iz);
            in_ = fmaf(wi2[k], g[k], in_);
            hr_ = fmaf(wh0[k], h[k], hr_);
            hz  = fmaf(wh1[k], h[k], hz);
            hn  = fmaf(wh2[k], h[k], hn);
        }
        float r  = 1.f / (1.f + __expf(-(ir + hr_)));
        float z  = 1.f / (1.f + __expf(-(iz + hz)));
        float nn = tanhf(in_ + r * hn);
        float hj = hr[j];  // reload from global: avoids dynamic register indexing
        float hnew = (1.f - z) * nn + z * hj;
        o1[j] = hnew;
        o2[j] = hnew;
    }
}

extern "C" void kernel_launch(void* const* d_in, const int* in_sizes, int n_in,
                              void* d_out, int out_size, void* d_ws, size_t ws_size,
                              hipStream_t stream) {
    const float* x   = (const float*)d_in[0];
    const int*   ei  = (const int*)d_in[1];
    const float* hs  = (const float*)d_in[2];
    const float* Wg  = (const float*)d_in[3];
    const float* bg  = (const float*)d_in[4];
    const float* Wih = (const float*)d_in[5];
    const float* Whh = (const float*)d_in[6];
    const float* bih = (const float*)d_in[7];
    const float* bhh = (const float*)d_in[8];
    float* out = (float*)d_out;

    char* ws = (char*)d_ws;
    float* xt  = (float*)(ws);                 // 25,600,000 B
    float* agg = (float*)(ws + 25600000);      // 25,600,000 B
    int*   deg = (int*)  (ws + 51200000);      //    400,000 B
    float* dis = (float*)(ws + 51600000);      //    400,000 B

    hipLaunchKernelGGL(k_deg_init, dim3((NN + 255) / 256), dim3(256), 0, stream, deg);
    hipLaunchKernelGGL(k_count,    dim3(1024), dim3(256), 0, stream, ei + NE, deg);
    hipLaunchKernelGGL(k_dis,      dim3((NN + 255) / 256), dim3(256), 0, stream, deg, dis);
    hipLaunchKernelGGL(k_xt,       dim3(1024), dim3(256), 0, stream, x, Wg, xt);
    hipLaunchKernelGGL(k_self,     dim3((NN * HH + 255) / 256), dim3(256), 0, stream, dis, xt, agg);
    hipLaunchKernelGGL(k_edge,     dim3(2048), dim3(256), 0, stream, ei, dis, xt, agg);
    hipLaunchKernelGGL(k_gru,      dim3((NN + 255) / 256), dim3(256), 0, stream,
                       agg, bg, hs, Wih, Whh, bih, bhh, out);
}

// Round 2
// 1244.459 us; speedup vs baseline: 1.2179x; 1.2179x over previous
//
#include <hip/hip_runtime.h>
#include <cmath>

constexpr int NN  = 100000;
constexpr int FIN = 128;
constexpr int HH  = 64;
constexpr int NE  = 3200000;
constexpr int NB  = (NN + 255) / 256;  // 391 scan blocks

// deg[col[e]] += 1  (in-degree, self-loop NOT included; dis uses deg+1)
__global__ void k_count(const int* __restrict__ col, int* __restrict__ deg) {
    int e = blockIdx.x * blockDim.x + threadIdx.x;
    if (e < NE) atomicAdd(&deg[col[e]], 1);
}

// dis[i] = rsqrt(deg[i] + 1)
__global__ void k_dis(const int* __restrict__ deg, float* __restrict__ dis) {
    int i = blockIdx.x * blockDim.x + threadIdx.x;
    if (i < NN) dis[i] = rsqrtf((float)(deg[i] + 1));
}

// per-256-chunk sums of deg
__global__ void k_bsum(const int* __restrict__ deg, int* __restrict__ bsum) {
    __shared__ int s[256];
    int i = blockIdx.x * 256 + threadIdx.x;
    s[threadIdx.x] = (i < NN) ? deg[i] : 0;
    __syncthreads();
    for (int off = 128; off > 0; off >>= 1) {
        if (threadIdx.x < off) s[threadIdx.x] += s[threadIdx.x + off];
        __syncthreads();
    }
    if (threadIdx.x == 0) bsum[blockIdx.x] = s[0];
}

// exclusive scan of the NB block sums (single block, Hillis-Steele over 512)
__global__ void k_bscan(const int* __restrict__ bsum, int* __restrict__ boff) {
    __shared__ int s[512];
    int t = threadIdx.x;
    int v = (t < NB) ? bsum[t] : 0;
    s[t] = v;
    __syncthreads();
    for (int off = 1; off < 512; off <<= 1) {
        int add = (t >= off) ? s[t - off] : 0;
        __syncthreads();
        s[t] += add;
        __syncthreads();
    }
    if (t < NB) boff[t] = s[t] - v;  // exclusive
}

// rowptr[i] = boff[block] + exclusive_scan_within_block(deg)
__global__ void k_rowptr(const int* __restrict__ deg, const int* __restrict__ boff,
                         int* __restrict__ rowptr) {
    __shared__ int s[256];
    int t = threadIdx.x;
    int i = blockIdx.x * 256 + t;
    int v = (i < NN) ? deg[i] : 0;
    s[t] = v;
    __syncthreads();
    for (int off = 1; off < 256; off <<= 1) {
        int add = (t >= off) ? s[t - off] : 0;
        __syncthreads();
        s[t] += add;
        __syncthreads();
    }
    if (i < NN) rowptr[i] = boff[blockIdx.x] + s[t] - v;
}

// scatter edge sources into CSR slots
__global__ void k_fill(const int* __restrict__ ei, const int* __restrict__ rowptr,
                       int* __restrict__ cur, int* __restrict__ csr) {
    int e = blockIdx.x * blockDim.x + threadIdx.x;
    if (e >= NE) return;
    int r = ei[e];        // source
    int c = ei[NE + e];   // target
    int p = atomicAdd(&cur[c], 1);
    csr[rowptr[c] + p] = r;
}

// xt = x @ W_gcn ; x row staged in LDS, W in LDS
__global__ void __launch_bounds__(256) k_xt(const float* __restrict__ x,
                                            const float* __restrict__ W,
                                            float* __restrict__ xt) {
    __shared__ float Wl[FIN * HH];  // 32 KB
    __shared__ float xs[4][FIN];    // 2 KB
    for (int t = threadIdx.x; t < FIN * HH; t += 256) Wl[t] = W[t];
    __syncthreads();
    int lane = threadIdx.x & 63;
    int w    = threadIdx.x >> 6;
    for (int row = blockIdx.x * 4 + w; row < NN; row += gridDim.x * 4) {
        float2 v = ((const float2*)(x + (size_t)row * FIN))[lane];
        xs[w][2 * lane]     = v.x;     // per-wave LDS, wave-synchronous: no barrier
        xs[w][2 * lane + 1] = v.y;
        float acc = 0.f;
#pragma unroll
        for (int k = 0; k < FIN; ++k) acc = fmaf(xs[w][k], Wl[k * HH + lane], acc);
        xt[(size_t)row * HH + lane] = acc;
    }
}

// gather aggregation + bias + relu: g[n] = relu(dis[n]*(dis[n]*xt[n] + sum dis[r]*xt[r]) + b)
__global__ void __launch_bounds__(256) k_gather(const int* __restrict__ csr,
                                                const int* __restrict__ rowptr,
                                                const int* __restrict__ deg,
                                                const float* __restrict__ dis,
                                                const float* __restrict__ xt,
                                                const float* __restrict__ bg,
                                                float* __restrict__ g) {
    __shared__ int   lid[4][64];
    __shared__ float lds[4][64];
    int lane = threadIdx.x & 63;
    int w    = threadIdx.x >> 6;
    int n    = blockIdx.x * 4 + w;
    if (n >= NN) return;
    float dn  = dis[n];
    float acc = dn * xt[(size_t)n * HH + lane];  // self-loop (dn applied again at end)
    int start = rowptr[n];
    int cnt   = deg[n];
    for (int c0 = 0; c0 < cnt; c0 += 64) {
        int m = min(64, cnt - c0);
        int   id = (lane < m) ? csr[start + c0 + lane] : 0;
        float dr = (lane < m) ? dis[id] : 0.f;
        lid[w][lane] = id;   // per-wave slot, wave-synchronous
        lds[w][lane] = dr;
        for (int i = 0; i < m; ++i) {
            int   src = lid[w][i];
            float d   = lds[w][i];
            acc = fmaf(d, xt[(size_t)src * HH + lane], acc);
        }
    }
    g[(size_t)n * HH + lane] = fmaxf(fmaf(dn, acc, bg[lane]), 0.f);
}

// GRU step; g pre-activated; write out twice
__global__ void __launch_bounds__(256) k_gru(
    const float* __restrict__ gbuf, const float* __restrict__ hprev,
    const float* __restrict__ Wih, const float* __restrict__ Whh,
    const float* __restrict__ bih, const float* __restrict__ bhh,
    float* __restrict__ out) {
    int n = blockIdx.x * blockDim.x + threadIdx.x;
    if (n >= NN) return;
    float g[HH], h[HH];
    const float* gr = gbuf + (size_t)n * HH;
    const float* hr = hprev + (size_t)n * HH;
#pragma unroll
    for (int k = 0; k < HH; k += 4) {
        float4 a = *(const float4*)(gr + k);
        float4 b = *(const float4*)(hr + k);
        g[k] = a.x; g[k + 1] = a.y; g[k + 2] = a.z; g[k + 3] = a.w;
        h[k] = b.x; h[k + 1] = b.y; h[k + 2] = b.z; h[k + 3] = b.w;
    }
    float* o1 = out + (size_t)n * HH;
    float* o2 = out + (size_t)NN * HH + (size_t)n * HH;
#pragma unroll 1
    for (int j = 0; j < HH; ++j) {
        float ir = bih[j], iz = bih[j + HH], in_ = bih[j + 2 * HH];
        float hr_ = bhh[j], hz = bhh[j + HH], hn = bhh[j + 2 * HH];
        const float* wi0 = Wih + (size_t)j * HH;
        const float* wi1 = Wih + (size_t)(j + HH) * HH;
        const float* wi2 = Wih + (size_t)(j + 2 * HH) * HH;
        const float* wh0 = Whh + (size_t)j * HH;
        const float* wh1 = Whh + (size_t)(j + HH) * HH;
        const float* wh2 = Whh + (size_t)(j + 2 * HH) * HH;
#pragma unroll
        for (int k = 0; k < HH; ++k) {
            ir  = fmaf(wi0[k], g[k], ir);
            iz  = fmaf(wi1[k], g[k], iz);
            in_ = fmaf(wi2[k], g[k], in_);
            hr_ = fmaf(wh0[k], h[k], hr_);
            hz  = fmaf(wh1[k], h[k], hz);
            hn  = fmaf(wh2[k], h[k], hn);
        }
        float r  = 1.f / (1.f + __expf(-(ir + hr_)));
        float z  = 1.f / (1.f + __expf(-(iz + hz)));
        float nn = tanhf(in_ + r * hn);
        float hj = hr[j];  // reload: avoids dynamic register indexing
        float hnew = (1.f - z) * nn + z * hj;
        o1[j] = hnew;
        o2[j] = hnew;
    }
}

extern "C" void kernel_launch(void* const* d_in, const int* in_sizes, int n_in,
                              void* d_out, int out_size, void* d_ws, size_t ws_size,
                              hipStream_t stream) {
    const float* x   = (const float*)d_in[0];
    const int*   ei  = (const int*)d_in[1];
    const float* hs  = (const float*)d_in[2];
    const float* Wg  = (const float*)d_in[3];
    const float* bg  = (const float*)d_in[4];
    const float* Wih = (const float*)d_in[5];
    const float* Whh = (const float*)d_in[6];
    const float* bih = (const float*)d_in[7];
    const float* bhh = (const float*)d_in[8];
    float* out = (float*)d_out;

    char* ws = (char*)d_ws;
    float* xt     = (float*)(ws);                  // 25,600,000 B
    float* gbuf   = (float*)(ws + 25600000);       // 25,600,000 B
    int*   csr    = (int*)  (ws + 51200000);       // 12,800,000 B
    int*   deg    = (int*)  (ws + 64000000);       //    400,000 B
    int*   rowptr = (int*)  (ws + 64400000);       //    400,000 B
    int*   cur    = (int*)  (ws + 64800000);       //    400,000 B
    float* dis    = (float*)(ws + 65200000);       //    400,000 B
    int*   bsum   = (int*)  (ws + 65600000);       //      2,048 B
    int*   boff   = (int*)  (ws + 65604096);       //      2,048 B

    hipMemsetAsync(deg, 0, NN * sizeof(int), stream);
    hipMemsetAsync(cur, 0, NN * sizeof(int), stream);

    hipLaunchKernelGGL(k_count,  dim3((NE + 255) / 256), dim3(256), 0, stream, ei + NE, deg);
    hipLaunchKernelGGL(k_dis,    dim3((NN + 255) / 256), dim3(256), 0, stream, deg, dis);
    hipLaunchKernelGGL(k_bsum,   dim3(NB), dim3(256), 0, stream, deg, bsum);
    hipLaunchKernelGGL(k_bscan,  dim3(1), dim3(512), 0, stream, bsum, boff);
    hipLaunchKernelGGL(k_rowptr, dim3(NB), dim3(256), 0, stream, deg, boff, rowptr);
    hipLaunchKernelGGL(k_fill,   dim3((NE + 255) / 256), dim3(256), 0, stream, ei, rowptr, cur, csr);
    hipLaunchKernelGGL(k_xt,     dim3(2048), dim3(256), 0, stream, x, Wg, xt);
    hipLaunchKernelGGL(k_gather, dim3((NN + 3) / 4), dim3(256), 0, stream,
                       csr, rowptr, deg, dis, xt, bg, gbuf);
    hipLaunchKernelGGL(k_gru,    dim3((NN + 255) / 256), dim3(256), 0, stream,
                       gbuf, hs, Wih, Whh, bih, bhh, out);
}

// Round 3
// 937.135 us; speedup vs baseline: 1.6173x; 1.3279x over previous
//
#include <hip/hip_runtime.h>
#include <cmath>

constexpr int NN  = 100000;
constexpr int FIN = 128;
constexpr int HH  = 64;
constexpr int NE  = 3200000;
constexpr int NB  = (NN + 255) / 256;  // 391 scan blocks

// deg[col[e]] += 1  (in-degree, self-loop NOT included; dis uses deg+1)
__global__ void k_count(const int* __restrict__ col, int* __restrict__ deg) {
    int e = blockIdx.x * blockDim.x + threadIdx.x;
    if (e < NE) atomicAdd(&deg[col[e]], 1);
}

// dis[i] = rsqrt(deg[i] + 1)
__global__ void k_dis(const int* __restrict__ deg, float* __restrict__ dis) {
    int i = blockIdx.x * blockDim.x + threadIdx.x;
    if (i < NN) dis[i] = rsqrtf((float)(deg[i] + 1));
}

// per-256-chunk sums of deg
__global__ void k_bsum(const int* __restrict__ deg, int* __restrict__ bsum) {
    __shared__ int s[256];
    int i = blockIdx.x * 256 + threadIdx.x;
    s[threadIdx.x] = (i < NN) ? deg[i] : 0;
    __syncthreads();
    for (int off = 128; off > 0; off >>= 1) {
        if (threadIdx.x < off) s[threadIdx.x] += s[threadIdx.x + off];
        __syncthreads();
    }
    if (threadIdx.x == 0) bsum[blockIdx.x] = s[0];
}

// exclusive scan of the NB block sums (single block, Hillis-Steele over 512)
__global__ void k_bscan(const int* __restrict__ bsum, int* __restrict__ boff) {
    __shared__ int s[512];
    int t = threadIdx.x;
    int v = (t < NB) ? bsum[t] : 0;
    s[t] = v;
    __syncthreads();
    for (int off = 1; off < 512; off <<= 1) {
        int add = (t >= off) ? s[t - off] : 0;
        __syncthreads();
        s[t] += add;
        __syncthreads();
    }
    if (t < NB) boff[t] = s[t] - v;  // exclusive
}

// rowptr[i] = boff[block] + exclusive_scan_within_block(deg)
__global__ void k_rowptr(const int* __restrict__ deg, const int* __restrict__ boff,
                         int* __restrict__ rowptr) {
    __shared__ int s[256];
    int t = threadIdx.x;
    int i = blockIdx.x * 256 + t;
    int v = (i < NN) ? deg[i] : 0;
    s[t] = v;
    __syncthreads();
    for (int off = 1; off < 256; off <<= 1) {
        int add = (t >= off) ? s[t - off] : 0;
        __syncthreads();
        s[t] += add;
        __syncthreads();
    }
    if (i < NN) rowptr[i] = boff[blockIdx.x] + s[t] - v;
}

// scatter edge sources into CSR slots
__global__ void k_fill(const int* __restrict__ ei, const int* __restrict__ rowptr,
                       int* __restrict__ cur, int* __restrict__ csr) {
    int e = blockIdx.x * blockDim.x + threadIdx.x;
    if (e >= NE) return;
    int r = ei[e];        // source
    int c = ei[NE + e];   // target
    int p = atomicAdd(&cur[c], 1);
    csr[rowptr[c] + p] = r;
}

// xt = x @ W_gcn ; x row staged in LDS, W in LDS
__global__ void __launch_bounds__(256) k_xt(const float* __restrict__ x,
                                            const float* __restrict__ W,
                                            float* __restrict__ xt) {
    __shared__ float Wl[FIN * HH];  // 32 KB
    __shared__ float xs[4][FIN];    // 2 KB
    for (int t = threadIdx.x; t < FIN * HH; t += 256) Wl[t] = W[t];
    __syncthreads();
    int lane = threadIdx.x & 63;
    int w    = threadIdx.x >> 6;
    for (int row = blockIdx.x * 4 + w; row < NN; row += gridDim.x * 4) {
        float2 v = ((const float2*)(x + (size_t)row * FIN))[lane];
        xs[w][2 * lane]     = v.x;     // per-wave LDS, wave-synchronous: no barrier
        xs[w][2 * lane + 1] = v.y;
        float acc = 0.f;
#pragma unroll
        for (int k = 0; k < FIN; ++k) acc = fmaf(xs[w][k], Wl[k * HH + lane], acc);
        xt[(size_t)row * HH + lane] = acc;
    }
}

// gather aggregation + bias + relu: g[n] = relu(dis[n]*(dis[n]*xt[n] + sum dis[r]*xt[r]) + b)
__global__ void __launch_bounds__(256) k_gather(const int* __restrict__ csr,
                                                const int* __restrict__ rowptr,
                                                const int* __restrict__ deg,
                                                const float* __restrict__ dis,
                                                const float* __restrict__ xt,
                                                const float* __restrict__ bg,
                                                float* __restrict__ g) {
    __shared__ int   lid[4][64];
    __shared__ float lds[4][64];
    int lane = threadIdx.x & 63;
    int w    = threadIdx.x >> 6;
    int n    = blockIdx.x * 4 + w;
    if (n >= NN) return;
    float dn  = dis[n];
    float acc = dn * xt[(size_t)n * HH + lane];  // self-loop (dn applied again at end)
    int start = rowptr[n];
    int cnt   = deg[n];
    for (int c0 = 0; c0 < cnt; c0 += 64) {
        int m = min(64, cnt - c0);
        int   id = (lane < m) ? csr[start + c0 + lane] : 0;
        float dr = (lane < m) ? dis[id] : 0.f;
        lid[w][lane] = id;   // per-wave slot, wave-synchronous
        lds[w][lane] = dr;
        for (int i = 0; i < m; ++i) {
            int   src = lid[w][i];
            float d   = lds[w][i];
            acc = fmaf(d, xt[(size_t)src * HH + lane], acc);
        }
    }
    g[(size_t)n * HH + lane] = fmaxf(fmaf(dn, acc, bg[lane]), 0.f);
}

// GRU step, thread-per-node; all global I/O via swizzled 64 KB LDS buffer.
// LDS word for (node row n, col k): n*64 + ((k + n) & 63)  -> 2-way banks (free)
__global__ void __launch_bounds__(256) k_gru(
    const float* __restrict__ gbuf, const float* __restrict__ hprev,
    const float* __restrict__ Wih, const float* __restrict__ Whh,
    const float* __restrict__ bih, const float* __restrict__ bhh,
    float* __restrict__ out) {
    __shared__ float A[256 * 64];  // 64 KB
    int t  = threadIdx.x;
    int n0 = blockIdx.x * 256;
    int nvalid = min(256, NN - n0);

    float g[HH], h[HH];

    // ---- stage g: coalesced global -> swizzled LDS ----
    for (int s = 0; s < 64; ++s) {
        int flat = t + 256 * s;        // wave reads 256 consecutive floats
        int node = flat >> 6;          // uniform within a wave
        int j    = flat & 63;          // = lane
        float v = (n0 + node < NN) ? gbuf[(size_t)n0 * HH + flat] : 0.f;
        A[node * 64 + ((j + node) & 63)] = v;
    }
    __syncthreads();
    if (t < nvalid) {
#pragma unroll
        for (int k = 0; k < HH; ++k) g[k] = A[t * 64 + ((k + t) & 63)];
    }
    __syncthreads();
    // ---- stage h ----
    for (int s = 0; s < 64; ++s) {
        int flat = t + 256 * s;
        int node = flat >> 6;
        int j    = flat & 63;
        float v = (n0 + node < NN) ? hprev[(size_t)n0 * HH + flat] : 0.f;
        A[node * 64 + ((j + node) & 63)] = v;
    }
    __syncthreads();
    if (t < nvalid) {
#pragma unroll
        for (int k = 0; k < HH; ++k) h[k] = A[t * 64 + ((k + t) & 63)];

        // ---- compute: j-loop rolled, k-loop unrolled; weights are wave-uniform
        //      (compiler emits scalar s_load broadcasts) ----
#pragma unroll 1
        for (int j = 0; j < HH; ++j) {
            float ir = bih[j], iz = bih[j + HH], in_ = bih[j + 2 * HH];
            float hr_ = bhh[j], hz = bhh[j + HH], hn = bhh[j + 2 * HH];
            const float* wi0 = Wih + (size_t)j * HH;
            const float* wi1 = Wih + (size_t)(j + HH) * HH;
            const float* wi2 = Wih + (size_t)(j + 2 * HH) * HH;
            const float* wh0 = Whh + (size_t)j * HH;
            const float* wh1 = Whh + (size_t)(j + HH) * HH;
            const float* wh2 = Whh + (size_t)(j + 2 * HH) * HH;
#pragma unroll
            for (int k = 0; k < HH; ++k) {
                ir  = fmaf(wi0[k], g[k], ir);
                iz  = fmaf(wi1[k], g[k], iz);
                in_ = fmaf(wi2[k], g[k], in_);
                hr_ = fmaf(wh0[k], h[k], hr_);
                hz  = fmaf(wh1[k], h[k], hz);
                hn  = fmaf(wh2[k], h[k], hn);
            }
            float r  = 1.f / (1.f + __expf(-(ir + hr_)));
            float z  = 1.f / (1.f + __expf(-(iz + hz)));
            float nn = tanhf(in_ + r * hn);
            int   wi = t * 64 + ((j + t) & 63);
            float hj = A[wi];            // h[j] from LDS (own row, dynamic j)
            A[wi] = (1.f - z) * nn + z * hj;  // overwrite own row in place
        }
    }
    __syncthreads();
    // ---- epilogue: swizzled LDS -> coalesced global, full lines, written twice ----
    for (int s = 0; s < 64; ++s) {
        int flat = t + 256 * s;
        int node = flat >> 6;
        int j    = flat & 63;
        if (n0 + node < NN) {
            float v = A[node * 64 + ((j + node) & 63)];
            out[(size_t)n0 * HH + flat] = v;
            out[(size_t)NN * HH + (size_t)n0 * HH + flat] = v;
        }
    }
}

extern "C" void kernel_launch(void* const* d_in, const int* in_sizes, int n_in,
                              void* d_out, int out_size, void* d_ws, size_t ws_size,
                              hipStream_t stream) {
    const float* x   = (const float*)d_in[0];
    const int*   ei  = (const int*)d_in[1];
    const float* hs  = (const float*)d_in[2];
    const float* Wg  = (const float*)d_in[3];
    const float* bg  = (const float*)d_in[4];
    const float* Wih = (const float*)d_in[5];
    const float* Whh = (const float*)d_in[6];
    const float* bih = (const float*)d_in[7];
    const float* bhh = (const float*)d_in[8];
    float* out = (float*)d_out;

    char* ws = (char*)d_ws;
    float* xt     = (float*)(ws);                  // 25,600,000 B
    float* gbuf   = (float*)(ws + 25600000);       // 25,600,000 B
    int*   csr    = (int*)  (ws + 51200000);       // 12,800,000 B
    int*   deg    = (int*)  (ws + 64000000);       //    400,000 B
    int*   rowptr = (int*)  (ws + 64400000);       //    400,000 B
    int*   cur    = (int*)  (ws + 64800000);       //    400,000 B
    float* dis    = (float*)(ws + 65200000);       //    400,000 B
    int*   bsum   = (int*)  (ws + 65600000);       //      2,048 B
    int*   boff   = (int*)  (ws + 65604096);       //      2,048 B

    hipMemsetAsync(deg, 0, NN * sizeof(int), stream);
    hipMemsetAsync(cur, 0, NN * sizeof(int), stream);

    hipLaunchKernelGGL(k_count,  dim3((NE + 255) / 256), dim3(256), 0, stream, ei + NE, deg);
    hipLaunchKernelGGL(k_dis,    dim3((NN + 255) / 256), dim3(256), 0, stream, deg, dis);
    hipLaunchKernelGGL(k_bsum,   dim3(NB), dim3(256), 0, stream, deg, bsum);
    hipLaunchKernelGGL(k_bscan,  dim3(1), dim3(512), 0, stream, bsum, boff);
    hipLaunchKernelGGL(k_rowptr, dim3(NB), dim3(256), 0, stream, deg, boff, rowptr);
    hipLaunchKernelGGL(k_fill,   dim3((NE + 255) / 256), dim3(256), 0, stream, ei, rowptr, cur, csr);
    hipLaunchKernelGGL(k_xt,     dim3(2048), dim3(256), 0, stream, x, Wg, xt);
    hipLaunchKernelGGL(k_gather, dim3((NN + 3) / 4), dim3(256), 0, stream,
                       csr, rowptr, deg, dis, xt, bg, gbuf);
    hipLaunchKernelGGL(k_gru,    dim3(NB), dim3(256), 0, stream,
                       gbuf, hs, Wih, Whh, bih, bhh, out);
}